// Round 3
// baseline (436.752 us; speedup 1.0000x reference)
//
#include <hip/hip_runtime.h>
#include <hip/hip_bf16.h>

#define NN 10000
#define NE 320000

typedef __bf16 bf16x8 __attribute__((ext_vector_type(8)));
typedef float  f32x4  __attribute__((ext_vector_type(4)));

__device__ __forceinline__ float bf2f(ushort u){
  union { uint i; float f; } c; c.i = ((uint)u) << 16; return c.f;
}
__device__ __forceinline__ ushort f2bf(float f){
  union { float f; uint i; } c; c.f = f;
  uint x = c.i;
  return (ushort)((x + 0x7FFFu + ((x >> 16) & 1u)) >> 16);
}
__device__ __forceinline__ float gelu_erf(float x){
  return 0.5f * x * (1.0f + erff(x * 0.70710678118654752f));
}
#define MFMA16(a,b,c) __builtin_amdgcn_mfma_f32_16x16x32_bf16((a),(b),(c),0,0,0)

// ---------------- dtype detection: flag=1 -> inputs are fp32 ----------------
__global__ void k_detect(const uint* __restrict__ w, int* __restrict__ flag){
  int t = threadIdx.x;
  uint cnt = 0;
  for (int i = t; i < 4096; i += 256){
    uint v = w[i * 63];
    uint e = (v >> 7) & 0xFF;
    if (e >= 100 && e <= 140) cnt++;
  }
  __shared__ uint red[256];
  red[t] = cnt; __syncthreads();
  for (int s = 128; s > 0; s >>= 1){
    if (t < s) red[t] += red[t + s];
    __syncthreads();
  }
  if (t == 0) *flag = (red[0] < 2048) ? 1 : 0;
}

// ---------------- canonicalize NF to bf16 ----------------
__global__ void k_cvt4(const void* __restrict__ in, ushort* __restrict__ out,
                       int n4, const int* __restrict__ flag){
  int i = blockIdx.x * 256 + threadIdx.x;
  if (i >= n4) return;
  if (*flag){
    float4 v = ((const float4*)in)[i];
    ushort4 o;
    o.x = f2bf(v.x); o.y = f2bf(v.y); o.z = f2bf(v.z); o.w = f2bf(v.w);
    ((ushort4*)out)[i] = o;
  } else {
    ((ushort4*)out)[i] = ((const ushort4*)in)[i];
  }
}

// small params: SB = [b1|b2|q_b|kv_b|o_b1|o_b2|ln_g|ln_b] (8x128), KVW2 = kv_w[128:192][:]
__global__ void k_cvt_params(const void* b1, const void* b2, const void* qb, const void* kvb,
                             const void* ob1, const void* ob2, const void* lg, const void* lb,
                             const void* kvw, ushort* __restrict__ SB, ushort* __restrict__ KVW2,
                             const int* __restrict__ flag){
  int i = blockIdx.x * 256 + threadIdx.x;
  int f = *flag;
  if (i < 1024){
    const void* ps[8] = {b1, b2, qb, kvb, ob1, ob2, lg, lb};
    const void* p = ps[i >> 7];
    int j = i & 127;
    SB[i] = f ? f2bf(((const float*)p)[j]) : ((const ushort*)p)[j];
  } else if (i < 1024 + 64 * 128){
    int j = i - 1024;
    KVW2[j] = f ? f2bf(((const float*)kvw)[16384 + j]) : ((const ushort*)kvw)[16384 + j];
  }
}

// transpose weight [K][128] -> bf16 [128][K], flag-aware read
__global__ void k_tr(const void* __restrict__ in, ushort* __restrict__ out, int K,
                     const int* __restrict__ flag){
  int idx = blockIdx.x * 256 + threadIdx.x;
  if (idx < 128 * K){
    int j = idx / K, k = idx - j * K;
    out[idx] = *flag ? f2bf(((const float*)in)[k * 128 + j])
                     : ((const ushort*)in)[k * 128 + j];
  }
}

// ---------------- CSR build ----------------
__global__ void k_count(const int* __restrict__ dst, int* __restrict__ cnt,
                        int* __restrict__ last){
  int e = blockIdx.x * 256 + threadIdx.x;
  if (e < NE){
    int d = dst[e];
    atomicAdd(&cnt[d], 1);
    atomicMax(&last[d], e);
  }
}

__global__ __launch_bounds__(1024) void k_scan(const int* __restrict__ cnt,
                                               int* __restrict__ rowptr,
                                               int* __restrict__ fill){
  __shared__ int sc[1024];
  int t = threadIdx.x;
  int base = t * 10;
  int v[10]; int tot = 0;
  #pragma unroll
  for (int j = 0; j < 10; ++j){
    int idx = base + j;
    v[j] = (idx < NN) ? cnt[idx] : 0;
    tot += v[j];
  }
  sc[t] = tot; __syncthreads();
  for (int off = 1; off < 1024; off <<= 1){
    int x = (t >= off) ? sc[t - off] : 0;
    __syncthreads();
    sc[t] += x;
    __syncthreads();
  }
  int run = sc[t] - tot;   // exclusive
  #pragma unroll
  for (int j = 0; j < 10; ++j){
    int idx = base + j;
    if (idx < NN){ rowptr[idx] = run; fill[idx] = run; }
    run += v[j];
  }
  if (t == 1023) rowptr[NN] = sc[1023];
}

__global__ void k_fill(const int* __restrict__ dst, int* __restrict__ fill,
                       int* __restrict__ eSort){
  int e = blockIdx.x * 256 + threadIdx.x;
  if (e < NE){
    int p = atomicAdd(&fill[dst[e]], 1);
    eSort[p] = e;
  }
}

// ---------------- edge kernel: sorted edges, fused MLP, segmented reduce ----------------
__global__ __launch_bounds__(256) void k_edge(
    const ushort* __restrict__ NF, const ushort* __restrict__ EAb,
    const float* __restrict__ EAf,
    const int* __restrict__ srcI, const int* __restrict__ dstI,
    const int* __restrict__ eSort,
    const ushort* __restrict__ W1T, const ushort* __restrict__ W2T,
    const ushort* __restrict__ b1,  const ushort* __restrict__ b2,
    float* __restrict__ agg, const int* __restrict__ flag)
{
  __shared__ int eIdx[128], sIdx[128], dIdx[128];
  __shared__ __align__(16) char Hs[128 * 256];   // 32KB staging
  int t = threadIdx.x;
  int e0 = blockIdx.x * 128;
  if (t < 128){
    int e = eSort[e0 + t];
    eIdx[t] = e; sIdx[t] = srcI[e]; dIdx[t] = dstI[e];
  }
  __syncthreads();
  int F = *flag;   // wave-uniform

  int l = t & 63, w = t >> 6;
  int rw = w >> 1, cw = w & 1;
  int m = l & 15, g = l >> 4;
  const f32x4 FZ = {0.f, 0.f, 0.f, 0.f};

  f32x4 acc[4][4];
  #pragma unroll
  for (int i = 0; i < 4; ++i)
    #pragma unroll
    for (int j = 0; j < 4; ++j) acc[i][j] = FZ;

  int koff = g * 8;
  // GEMM1: K = 320 = [src 128 | dst 128 | ea 64]
  #pragma unroll
  for (int ks = 0; ks < 10; ++ks){
    bf16x8 af[4], bfr[4];
    #pragma unroll
    for (int rt = 0; rt < 4; ++rt){
      int rl = rw * 64 + rt * 16 + m;
      if (ks < 4){
        af[rt] = *reinterpret_cast<const bf16x8*>(NF + (size_t)sIdx[rl] * 128 + ks * 32 + koff);
      } else if (ks < 8){
        af[rt] = *reinterpret_cast<const bf16x8*>(NF + (size_t)dIdx[rl] * 128 + (ks - 4) * 32 + koff);
      } else {
        size_t eb = (size_t)eIdx[rl] * 64 + (ks - 8) * 32 + koff;
        if (F){
          float4 u0 = *reinterpret_cast<const float4*>(EAf + eb);
          float4 u1 = *reinterpret_cast<const float4*>(EAf + eb + 4);
          bf16x8 v;
          v[0] = (__bf16)u0.x; v[1] = (__bf16)u0.y; v[2] = (__bf16)u0.z; v[3] = (__bf16)u0.w;
          v[4] = (__bf16)u1.x; v[5] = (__bf16)u1.y; v[6] = (__bf16)u1.z; v[7] = (__bf16)u1.w;
          af[rt] = v;
        } else {
          af[rt] = *reinterpret_cast<const bf16x8*>(EAb + eb);
        }
      }
    }
    #pragma unroll
    for (int ct = 0; ct < 4; ++ct){
      int col = cw * 64 + ct * 16 + m;
      bfr[ct] = *reinterpret_cast<const bf16x8*>(W1T + (size_t)col * 320 + ks * 32 + koff);
    }
    #pragma unroll
    for (int rt = 0; rt < 4; ++rt)
      #pragma unroll
      for (int ct = 0; ct < 4; ++ct)
        acc[rt][ct] = MFMA16(af[rt], bfr[ct], acc[rt][ct]);
  }

  // bias + gelu -> H to LDS (XOR-swizzled for GEMM2 reads)
  #pragma unroll
  for (int ct = 0; ct < 4; ++ct){
    int col = cw * 64 + ct * 16 + m;
    float bb = bf2f(b1[col]);
    #pragma unroll
    for (int rt = 0; rt < 4; ++rt){
      #pragma unroll
      for (int r = 0; r < 4; ++r){
        int row = rw * 64 + rt * 16 + g * 4 + r;
        float h = gelu_erf(acc[rt][ct][r] + bb);
        int byte = (row * 256 + col * 2) ^ ((row & 7) << 4);
        *reinterpret_cast<ushort*>(&Hs[byte]) = f2bf(h);
      }
    }
  }
  __syncthreads();

  // GEMM2: K = 128
  f32x4 acc2[4][4];
  #pragma unroll
  for (int i = 0; i < 4; ++i)
    #pragma unroll
    for (int j = 0; j < 4; ++j) acc2[i][j] = FZ;

  #pragma unroll
  for (int ks = 0; ks < 4; ++ks){
    bf16x8 af[4], bfr[4];
    #pragma unroll
    for (int rt = 0; rt < 4; ++rt){
      int row = rw * 64 + rt * 16 + m;
      int byte = (row * 256 + (ks * 32 + koff) * 2) ^ ((row & 7) << 4);
      af[rt] = *reinterpret_cast<const bf16x8*>(&Hs[byte]);
    }
    #pragma unroll
    for (int ct = 0; ct < 4; ++ct){
      int col = cw * 64 + ct * 16 + m;
      bfr[ct] = *reinterpret_cast<const bf16x8*>(W2T + (size_t)col * 128 + ks * 32 + koff);
    }
    #pragma unroll
    for (int rt = 0; rt < 4; ++rt)
      #pragma unroll
      for (int ct = 0; ct < 4; ++ct)
        acc2[rt][ct] = MFMA16(af[rt], bfr[ct], acc2[rt][ct]);
  }
  __syncthreads();   // GEMM2 LDS reads done before overwrite

  // restage m = acc2 + b2 as bf16, swizzle spreads g-groups across bank octets
  #pragma unroll
  for (int ct = 0; ct < 4; ++ct){
    int col = cw * 64 + ct * 16 + m;
    float bb = bf2f(b2[col]);
    #pragma unroll
    for (int rt = 0; rt < 4; ++rt){
      #pragma unroll
      for (int r = 0; r < 4; ++r){
        int row = rw * 64 + rt * 16 + g * 4 + r;
        int byte = (row * 256 + col * 2) ^ (((row >> 2) & 3) << 5);
        *reinterpret_cast<ushort*>(&Hs[byte]) = f2bf(acc2[rt][ct][r] + bb);
      }
    }
  }
  __syncthreads();

  // segmented reduction over dst-sorted rows: wave-uniform run boundaries
  int c = t & 127, h = t >> 7;
  int rS = h * 64, rE = rS + 64;
  float run = 0.f;
  int cur = dIdx[rS];
  for (int r = rS; r < rE; ++r){
    int d = dIdx[r];
    if (d != cur){
      unsafeAtomicAdd(&agg[(size_t)cur * 128 + c], run);
      run = 0.f; cur = d;
    }
    int byte = (r * 256 + c * 2) ^ (((r >> 2) & 3) << 5);
    run += bf2f(*reinterpret_cast<const ushort*>(&Hs[byte]));
  }
  unsafeAtomicAdd(&agg[(size_t)cur * 128 + c], run);
}

// ---------------- generic node GEMM: A[M][K]bf16 @ WT[128][K] ----------------
// MODE 0: +bias -> bf16 ; MODE 1: +bias, gelu -> bf16 ; MODE 2: +bias -> f32
template<int K, int MODE>
__global__ __launch_bounds__(256) void k_gemm(
    const ushort* __restrict__ A, const ushort* __restrict__ WT,
    const ushort* __restrict__ bias, void* __restrict__ out, int M)
{
  int t = threadIdx.x;
  int l = t & 63, w = t >> 6;
  int m = l & 15, g = l >> 4;
  int row0 = blockIdx.x * 64 + w * 16;
  const f32x4 FZ = {0.f, 0.f, 0.f, 0.f};
  f32x4 acc[8];
  #pragma unroll
  for (int i = 0; i < 8; ++i) acc[i] = FZ;

  int arow = row0 + m; if (arow >= M) arow = M - 1;
  #pragma unroll
  for (int ks = 0; ks < K / 32; ++ks){
    int koff = ks * 32 + g * 8;
    bf16x8 a = *reinterpret_cast<const bf16x8*>(A + (size_t)arow * K + koff);
    #pragma unroll
    for (int nt = 0; nt < 8; ++nt){
      bf16x8 b = *reinterpret_cast<const bf16x8*>(WT + (size_t)(nt * 16 + m) * K + koff);
      acc[nt] = MFMA16(a, b, acc[nt]);
    }
  }
  #pragma unroll
  for (int nt = 0; nt < 8; ++nt){
    int col = nt * 16 + m;
    float bb = bf2f(bias[col]);
    #pragma unroll
    for (int r = 0; r < 4; ++r){
      int row = row0 + g * 4 + r;
      if (row < M){
        float v = acc[nt][r] + bb;
        if (MODE == 1) v = gelu_erf(v);
        if (MODE == 2) ((float*)out)[(size_t)row * 128 + col] = v;
        else           ((ushort*)out)[(size_t)row * 128 + col] = f2bf(v);
      }
    }
  }
}

// ---------------- attention logits at last-edges ----------------
__global__ __launch_bounds__(256) void k_attn(
    const ushort* __restrict__ Qb, const ushort* __restrict__ KV1,
    const ushort* __restrict__ EAb, const float* __restrict__ EAf,
    const ushort* __restrict__ KVW2,
    const int* __restrict__ srcI, const int* __restrict__ last,
    float* __restrict__ attn, const int* __restrict__ flag)
{
  __shared__ float ea_s[16][64];
  __shared__ int eN[16], sN[16];
  int t = threadIdx.x;
  int n0 = blockIdx.x * 16;
  if (t < 16){
    int e = last[n0 + t];
    eN[t] = e;
    sN[t] = (e >= 0) ? srcI[e] : 0;
  }
  __syncthreads();
  int F = *flag;
  for (int i = t; i < 1024; i += 256){
    int nn = i >> 6, k = i & 63;
    int e = eN[nn];
    int ee = (e >= 0) ? e : 0;
    float v = F ? EAf[(size_t)ee * 64 + k] : bf2f(EAb[(size_t)ee * 64 + k]);
    ea_s[nn][k] = (e >= 0) ? v : 0.0f;
  }
  __syncthreads();

  int j = t & 127;
  int half = t >> 7;
  float acc[8];
  #pragma unroll
  for (int i = 0; i < 8; ++i) acc[i] = 0.f;
  for (int k = 0; k < 64; ++k){
    float wv = bf2f(KVW2[(size_t)k * 128 + j]);
    #pragma unroll
    for (int nn = 0; nn < 8; ++nn) acc[nn] += ea_s[half * 8 + nn][k] * wv;
  }
  #pragma unroll
  for (int nn = 0; nn < 8; ++nn){
    int nl = half * 8 + nn;
    int n = n0 + nl;
    int e = eN[nl];
    float kvv = acc[nn] + bf2f(KV1[(size_t)sN[nl] * 128 + j]);
    float qv  = bf2f(Qb[(size_t)n * 128 + j]);
    float p = qv * kvv;
    p += __shfl_xor(p, 1); p += __shfl_xor(p, 2);
    p += __shfl_xor(p, 4); p += __shfl_xor(p, 8);
    if ((j & 15) == 0 && e >= 0) attn[(size_t)n * 8 + (j >> 4)] = p * 0.25f;
  }
}

// ---------------- softmax over node axis (per head), single block ----------------
__global__ __launch_bounds__(1024) void k_softmax(
    const float* __restrict__ attn, const int* __restrict__ last,
    float* __restrict__ attnw)
{
  __shared__ float red[128][8];
  __shared__ float Ms[8], Ss[8];
  int t = threadIdx.x;
  int h = t & 7, c = t >> 3;
  float mx = -3.0e38f;
  for (int n = c; n < NN; n += 128)
    if (last[n] >= 0) mx = fmaxf(mx, attn[(size_t)n * 8 + h]);
  red[c][h] = mx; __syncthreads();
  for (int s = 64; s > 0; s >>= 1){
    if (c < s) red[c][h] = fmaxf(red[c][h], red[c + s][h]);
    __syncthreads();
  }
  if (t < 8) Ms[t] = red[0][t];
  __syncthreads();
  float M = Ms[h];
  float sm = 0.f;
  for (int n = c; n < NN; n += 128)
    if (last[n] >= 0) sm += expf(attn[(size_t)n * 8 + h] - M);
  red[c][h] = sm; __syncthreads();
  for (int s = 64; s > 0; s >>= 1){
    if (c < s) red[c][h] += red[c + s][h];
    __syncthreads();
  }
  if (t < 8) Ss[t] = red[0][t];
  __syncthreads();
  for (int i = t; i < NN * 8; i += 1024){
    int n = i >> 3, hh = i & 7;
    float val = 0.0f;
    if (last[n] >= 0) val = expf(attn[i] - Ms[hh]) / Ss[hh];
    attnw[i] = val;
  }
}

// ---------------- build h_in = [NF | agg * attnw] ----------------
__global__ void k_hin(const ushort* __restrict__ NF, const float* __restrict__ agg,
                      const float* __restrict__ attnw, ushort* __restrict__ h_in)
{
  int i = blockIdx.x * 256 + threadIdx.x;
  if (i < NN * 256){
    int n = i >> 8, c = i & 255;
    if (c < 128) h_in[i] = NF[(size_t)n * 128 + c];
    else {
      int cc = c - 128;
      h_in[i] = f2bf(agg[(size_t)n * 128 + cc] * attnw[(size_t)n * 8 + (cc >> 4)]);
    }
  }
}

// ---------------- residual + LayerNorm, flag-aware output dtype ----------------
__global__ __launch_bounds__(64) void k_ln(
    const ushort* __restrict__ NF, const float* __restrict__ T2,
    const ushort* __restrict__ g, const ushort* __restrict__ b,
    void* __restrict__ out, const int* __restrict__ flag)
{
  int n = blockIdx.x, l = threadIdx.x;
  float x0 = bf2f(NF[(size_t)n * 128 + 2 * l])     + T2[(size_t)n * 128 + 2 * l];
  float x1 = bf2f(NF[(size_t)n * 128 + 2 * l + 1]) + T2[(size_t)n * 128 + 2 * l + 1];
  float s = x0 + x1, q = x0 * x0 + x1 * x1;
  #pragma unroll
  for (int msk = 1; msk < 64; msk <<= 1){
    s += __shfl_xor(s, msk);
    q += __shfl_xor(q, msk);
  }
  float mean = s * (1.0f / 128.0f);
  float var  = q * (1.0f / 128.0f) - mean * mean;
  float rs = rsqrtf(var + 1e-5f);
  float y0 = (x0 - mean) * rs * bf2f(g[2 * l])     + bf2f(b[2 * l]);
  float y1 = (x1 - mean) * rs * bf2f(g[2 * l + 1]) + bf2f(b[2 * l + 1]);
  if (*flag){
    ((float*)out)[(size_t)n * 128 + 2 * l]     = y0;
    ((float*)out)[(size_t)n * 128 + 2 * l + 1] = y1;
  } else {
    uint pack = (uint)f2bf(y0) | ((uint)f2bf(y1) << 16);
    *reinterpret_cast<uint*>(&((ushort*)out)[(size_t)n * 128 + 2 * l]) = pack;
  }
}

// ---------------- host ----------------
extern "C" void kernel_launch(void* const* d_in, const int* in_sizes, int n_in,
                              void* d_out, int out_size, void* d_ws, size_t ws_size,
                              hipStream_t stream)
{
  const void* NF0     = d_in[0];
  const void* EA0     = d_in[1];
  const void* msg_w1  = d_in[2];
  const void* msg_b1  = d_in[3];
  const void* msg_w2  = d_in[4];
  const void* msg_b2  = d_in[5];
  const void* q_w     = d_in[6];
  const void* q_b     = d_in[7];
  const void* kv_w    = d_in[8];
  const void* kv_b    = d_in[9];
  const void* o_w1    = d_in[10];
  const void* o_b1    = d_in[11];
  const void* o_w2    = d_in[12];
  const void* o_b2    = d_in[13];
  const void* ln_g    = d_in[14];
  const void* ln_b    = d_in[15];
  const int*  srcI    = (const int*)d_in[16];
  const int*  dstI    = srcI + NE;

  char* ws = (char*)d_ws;
  size_t off = 0;
  auto alloc = [&](size_t bytes) -> void* {
    void* p = ws + off;
    off = (off + bytes + 255) & ~(size_t)255;
    return p;
  };
  int*    flag  = (int*)   alloc(4);
  ushort* NFc   = (ushort*)alloc((size_t)NN * 128 * 2);
  ushort* SB    = (ushort*)alloc(8 * 128 * 2);
  ushort* KVW2  = (ushort*)alloc(64 * 128 * 2);
  ushort* W1T   = (ushort*)alloc(128 * 320 * 2);
  ushort* W2T   = (ushort*)alloc(128 * 128 * 2);
  ushort* QT    = (ushort*)alloc(128 * 128 * 2);
  ushort* KVT   = (ushort*)alloc(128 * 128 * 2);
  ushort* O1T   = (ushort*)alloc(128 * 256 * 2);
  ushort* O2T   = (ushort*)alloc(128 * 128 * 2);
  int*    last  = (int*)   alloc(NN * 4);
  int*    cnt   = (int*)   alloc(NN * 4);
  int*    rowptr= (int*)   alloc((NN + 1) * 4);
  int*    fill  = (int*)   alloc(NN * 4);
  int*    eSort = (int*)   alloc((size_t)NE * 4);
  float*  attn  = (float*) alloc(NN * 8 * 4);
  float*  attnw = (float*) alloc(NN * 8 * 4);
  ushort* Qb    = (ushort*)alloc((size_t)NN * 128 * 2);
  ushort* KV1   = (ushort*)alloc((size_t)NN * 128 * 2);
  float*  agg   = (float*) alloc((size_t)NN * 128 * 4);
  ushort* h_in  = (ushort*)alloc((size_t)NN * 256 * 2);
  ushort* T1    = (ushort*)alloc((size_t)NN * 128 * 2);
  float*  T2    = (float*)Qb;   // overlap: Qb+KV1 dead once T2 is written

  k_detect<<<1, 256, 0, stream>>>((const uint*)NF0, flag);

  hipMemsetAsync(last, 0xFF, NN * 4, stream);
  hipMemsetAsync(cnt, 0, NN * 4, stream);
  hipMemsetAsync(agg, 0, (size_t)NN * 128 * 4, stream);

  // CSR build (edges sorted by dst)
  k_count<<<(NE + 255) / 256, 256, 0, stream>>>(dstI, cnt, last);
  k_scan<<<1, 1024, 0, stream>>>(cnt, rowptr, fill);
  k_fill<<<(NE + 255) / 256, 256, 0, stream>>>(dstI, fill, eSort);

  // canonicalize NF + params
  k_cvt4<<<(NN * 128 / 4 + 255) / 256, 256, 0, stream>>>(NF0, NFc, NN * 128 / 4, flag);
  k_cvt_params<<<37, 256, 0, stream>>>(msg_b1, msg_b2, q_b, kv_b, o_b1, o_b2, ln_g, ln_b,
                                       kv_w, SB, KVW2, flag);

  // weight transposes (flag-aware read)
  k_tr<<<(128 * 320 + 255) / 256, 256, 0, stream>>>(msg_w1, W1T, 320, flag);
  k_tr<<<(128 * 128 + 255) / 256, 256, 0, stream>>>(msg_w2, W2T, 128, flag);
  k_tr<<<(128 * 128 + 255) / 256, 256, 0, stream>>>(q_w,    QT,  128, flag);
  k_tr<<<(128 * 128 + 255) / 256, 256, 0, stream>>>(kv_w,   KVT, 128, flag);
  k_tr<<<(128 * 256 + 255) / 256, 256, 0, stream>>>(o_w1,   O1T, 256, flag);
  k_tr<<<(128 * 128 + 255) / 256, 256, 0, stream>>>(o_w2,   O2T, 128, flag);

  // node pre-GEMMs: Qb = NF@q_w + q_b ; KV1 = NF@kv_w[:128] + kv_b
  k_gemm<128, 0><<<157, 256, 0, stream>>>(NFc, QT,  SB + 256, Qb,  NN);
  k_gemm<128, 0><<<157, 256, 0, stream>>>(NFc, KVT, SB + 384, KV1, NN);

  // edge MLP + segmented scatter (dst-sorted)
  k_edge<<<NE / 128, 256, 0, stream>>>(NFc, (const ushort*)EA0, (const float*)EA0,
                                       srcI, dstI, eSort, W1T, W2T, SB + 0, SB + 128,
                                       agg, flag);

  // attention
  k_attn<<<NN / 16, 256, 0, stream>>>(Qb, KV1, (const ushort*)EA0, (const float*)EA0,
                                      KVW2, srcI, last, attn, flag);
  k_softmax<<<1, 1024, 0, stream>>>(attn, last, attnw);

  // output MLP
  k_hin<<<(NN * 256 + 255) / 256, 256, 0, stream>>>(NFc, agg, attnw, h_in);
  k_gemm<256, 1><<<157, 256, 0, stream>>>(h_in, O1T, SB + 512, T1, NN);
  k_gemm<128, 2><<<157, 256, 0, stream>>>(T1,  O2T, SB + 640, T2, NN);

  // residual + LN
  k_ln<<<NN, 64, 0, stream>>>(NFc, T2, SB + 768, SB + 896, d_out, flag);
}

// Round 4
// 265.197 us; speedup vs baseline: 1.6469x; 1.6469x over previous
//
#include <hip/hip_runtime.h>
#include <hip/hip_bf16.h>

#define NN 10000
#define NE 320000

typedef __bf16 bf16x8 __attribute__((ext_vector_type(8)));
typedef float  f32x4  __attribute__((ext_vector_type(4)));

__device__ __forceinline__ float bf2f(ushort u){
  union { uint i; float f; } c; c.i = ((uint)u) << 16; return c.f;
}
__device__ __forceinline__ ushort f2bf(float f){
  union { float f; uint i; } c; c.f = f;
  uint x = c.i;
  return (ushort)((x + 0x7FFFu + ((x >> 16) & 1u)) >> 16);
}
__device__ __forceinline__ float gelu_erf(float x){
  return 0.5f * x * (1.0f + erff(x * 0.70710678118654752f));
}
__device__ __forceinline__ float gelu_tanh(float x){
  float y = 0.7978845608028654f * (x + 0.044715f * x * x * x);
  float e = __expf(2.f * y);
  float th = 1.f - 2.f / (e + 1.f);
  return 0.5f * x * (1.f + th);
}
__device__ __forceinline__ uint encf(float f){
  uint u = __float_as_uint(f);
  return (u & 0x80000000u) ? ~u : (u | 0x80000000u);
}
__device__ __forceinline__ float decf(uint u){
  return __uint_as_float((u & 0x80000000u) ? (u & 0x7FFFFFFFu) : ~u);
}
#define MFMA16(a,b,c) __builtin_amdgcn_mfma_f32_16x16x32_bf16((a),(b),(c),0,0,0)

// ---------------- dtype detection: flag=1 -> inputs are fp32 ----------------
__global__ void k_detect(const uint* __restrict__ w, int* __restrict__ flag){
  int t = threadIdx.x;
  uint cnt = 0;
  for (int i = t; i < 4096; i += 256){
    uint v = w[i * 63];
    uint e = (v >> 7) & 0xFF;
    if (e >= 100 && e <= 140) cnt++;
  }
  __shared__ uint red[256];
  red[t] = cnt; __syncthreads();
  for (int s = 128; s > 0; s >>= 1){
    if (t < s) red[t] += red[t + s];
    __syncthreads();
  }
  if (t == 0) *flag = (red[0] < 2048) ? 1 : 0;
}

// ---------------- one-shot prep: cvt + zeros + all weight transposes ----------------
// work layout (flat index):
//  [0,320000)            NFc as ushort4
//  [..+320000)           Gagg zero (float4)
//  [..+20016)            last=-1 | cnt=0 | Menc=0 | S=0
//  [..+1024)             SB = [b1|b2|q_b|kv_b|o_b1|o_b2|ln_g|ln_b]
//  [..+8192)             KVW2[k*128+j] = kv_w[(128+k)*128+j]
//  then transposes: W1aT,W1bT,W1cT,W2T,QT,KVT,O1T,O2T
__global__ void k_prep(
    const void* NF0, const void* w1, const void* w2, const void* qw, const void* kvw,
    const void* ow1, const void* ow2,
    const void* b1, const void* b2, const void* qb, const void* kvb,
    const void* ob1, const void* ob2, const void* lg, const void* lb,
    ushort* NFc, float* Gagg, int* last, int* cnt, uint* Menc, float* S,
    ushort* SB, ushort* KVW2,
    ushort* W1aT, ushort* W1bT, ushort* W1cT, ushort* W2T, ushort* QT, ushort* KVT,
    ushort* O1T, ushort* O2T, const int* flag)
{
  int f = *flag;
  int idx = blockIdx.x * 256 + threadIdx.x;
  if (idx < 320000){
    if (f){
      float4 v = ((const float4*)NF0)[idx];
      ushort4 o; o.x=f2bf(v.x); o.y=f2bf(v.y); o.z=f2bf(v.z); o.w=f2bf(v.w);
      ((ushort4*)NFc)[idx] = o;
    } else ((ushort4*)NFc)[idx] = ((const ushort4*)NF0)[idx];
    return;
  }
  idx -= 320000;
  if (idx < 320000){ float4 z = {0.f,0.f,0.f,0.f}; ((float4*)Gagg)[idx] = z; return; }
  idx -= 320000;
  if (idx < 20016){
    if (idx < 10000) last[idx] = -1;
    else if (idx < 20000) cnt[idx - 10000] = 0;
    else if (idx < 20008) Menc[idx - 20000] = 0u;
    else S[idx - 20008] = 0.f;
    return;
  }
  idx -= 20016;
  if (idx < 1024){
    const void* ps[8] = {b1,b2,qb,kvb,ob1,ob2,lg,lb};
    const void* p = ps[idx >> 7]; int j = idx & 127;
    SB[idx] = f ? f2bf(((const float*)p)[j]) : ((const ushort*)p)[j];
    return;
  }
  idx -= 1024;
  if (idx < 8192){
    KVW2[idx] = f ? f2bf(((const float*)kvw)[16384 + idx]) : ((const ushort*)kvw)[16384 + idx];
    return;
  }
  idx -= 8192;
  if (idx < 16384){ int c=idx>>7,k=idx&127; W1aT[idx] = f? f2bf(((const float*)w1)[k*128+c]) : ((const ushort*)w1)[k*128+c]; return; }
  idx -= 16384;
  if (idx < 16384){ int c=idx>>7,k=idx&127; W1bT[idx] = f? f2bf(((const float*)w1)[(128+k)*128+c]) : ((const ushort*)w1)[(128+k)*128+c]; return; }
  idx -= 16384;
  if (idx < 8192){ int c=idx>>6,k=idx&63;  W1cT[idx] = f? f2bf(((const float*)w1)[(256+k)*128+c]) : ((const ushort*)w1)[(256+k)*128+c]; return; }
  idx -= 8192;
  if (idx < 16384){ int c=idx>>7,k=idx&127; W2T[idx] = f? f2bf(((const float*)w2)[k*128+c]) : ((const ushort*)w2)[k*128+c]; return; }
  idx -= 16384;
  if (idx < 16384){ int c=idx>>7,k=idx&127; QT[idx]  = f? f2bf(((const float*)qw)[k*128+c]) : ((const ushort*)qw)[k*128+c]; return; }
  idx -= 16384;
  if (idx < 16384){ int c=idx>>7,k=idx&127; KVT[idx] = f? f2bf(((const float*)kvw)[k*128+c]) : ((const ushort*)kvw)[k*128+c]; return; }
  idx -= 16384;
  if (idx < 32768){ int c=idx>>8,k=idx&255; O1T[idx] = f? f2bf(((const float*)ow1)[k*128+c]) : ((const ushort*)ow1)[k*128+c]; return; }
  idx -= 32768;
  if (idx < 16384){ int c=idx>>7,k=idx&127; O2T[idx] = f? f2bf(((const float*)ow2)[k*128+c]) : ((const ushort*)ow2)[k*128+c]; return; }
}

// ---------------- CSR build ----------------
__global__ void k_count(const int* __restrict__ dst, int* __restrict__ cnt,
                        int* __restrict__ last){
  int e = blockIdx.x * 256 + threadIdx.x;
  if (e < NE){
    int d = dst[e];
    atomicAdd(&cnt[d], 1);
    atomicMax(&last[d], e);
  }
}

__global__ __launch_bounds__(1024) void k_scan(const int* __restrict__ cnt,
                                               int* __restrict__ fill){
  __shared__ int sc[1024];
  int t = threadIdx.x;
  int base = t * 10;
  int v[10]; int tot = 0;
  #pragma unroll
  for (int j = 0; j < 10; ++j){
    int idx = base + j;
    v[j] = (idx < NN) ? cnt[idx] : 0;
    tot += v[j];
  }
  sc[t] = tot; __syncthreads();
  for (int off = 1; off < 1024; off <<= 1){
    int x = (t >= off) ? sc[t - off] : 0;
    __syncthreads();
    sc[t] += x;
    __syncthreads();
  }
  int run = sc[t] - tot;   // exclusive
  #pragma unroll
  for (int j = 0; j < 10; ++j){
    int idx = base + j;
    if (idx < NN) fill[idx] = run;
    run += v[j];
  }
}

__global__ void k_fill(const int* __restrict__ dst, int* __restrict__ fill,
                       int* __restrict__ eSort){
  int e = blockIdx.x * 256 + threadIdx.x;
  if (e < NE){
    int p = atomicAdd(&fill[dst[e]], 1);
    eSort[p] = e;
  }
}

// ---------------- fused node pre-GEMMs: PA,PB,Qb,KV1 (one target per wave) ----------------
__global__ __launch_bounds__(256) void k_nodepack(
    const ushort* __restrict__ NFc,
    const ushort* __restrict__ W1aT, const ushort* __restrict__ W1bT,
    const ushort* __restrict__ QT,  const ushort* __restrict__ KVT,
    const ushort* __restrict__ SB,
    ushort* __restrict__ PA, ushort* __restrict__ PB,
    ushort* __restrict__ Qb, ushort* __restrict__ KV1)
{
  int t = threadIdx.x, l = t & 63, w = t >> 6;
  int m = l & 15, g = l >> 4;
  int row0 = blockIdx.x * 16;            // grid 625, 625*16 = 10000
  const ushort* WT = (w==0) ? W1aT : (w==1) ? W1bT : (w==2) ? QT : KVT;
  ushort*       OUT= (w==0) ? PA   : (w==1) ? PB   : (w==2) ? Qb : KV1;
  const f32x4 FZ = {0.f,0.f,0.f,0.f};
  f32x4 acc[8];
  #pragma unroll
  for (int i = 0; i < 8; ++i) acc[i] = FZ;
  int arow = row0 + m;
  #pragma unroll
  for (int ks = 0; ks < 4; ++ks){
    int koff = ks * 32 + g * 8;
    bf16x8 a = *reinterpret_cast<const bf16x8*>(NFc + (size_t)arow * 128 + koff);
    #pragma unroll
    for (int nt = 0; nt < 8; ++nt){
      bf16x8 b = *reinterpret_cast<const bf16x8*>(WT + (size_t)(nt*16+m) * 128 + koff);
      acc[nt] = MFMA16(a, b, acc[nt]);
    }
  }
  #pragma unroll
  for (int nt = 0; nt < 8; ++nt){
    int col = nt * 16 + m;
    float bb = (w==2) ? bf2f(SB[256+col]) : (w==3) ? bf2f(SB[384+col]) : 0.f;
    #pragma unroll
    for (int r = 0; r < 4; ++r){
      int row = row0 + g * 4 + r;
      OUT[(size_t)row * 128 + col] = f2bf(acc[nt][r] + bb);
    }
  }
}

// ---------------- edge kernel: pre = PA[s]+PB[d]+EA@W1c+b1 -> gelu -> seg-reduce -> Gagg ----------------
__global__ __launch_bounds__(256) void k_edge(
    const ushort* __restrict__ PA, const ushort* __restrict__ PB,
    const float* __restrict__ EAf, const ushort* __restrict__ EAb,
    const int* __restrict__ srcI, const int* __restrict__ dstI,
    const int* __restrict__ eSort,
    const ushort* __restrict__ W1cT, const ushort* __restrict__ SB,   // b1 = SB+0
    float* __restrict__ Gagg, const int* __restrict__ flag)
{
  __shared__ int sIdx[128], dIdx[128];
  __shared__ __align__(16) char Hs[128 * 256];   // PS, then G (bf16, XOR-swizzled)
  int t = threadIdx.x;
  int e0 = blockIdx.x * 128;
  int l = t & 63, w = t >> 6;
  int rw = w >> 1, cw = w & 1;
  int m = l & 15, g = l >> 4;
  int F = *flag;

  // each lane's 4 edge ids (for EA reads)
  int eId[4];
  #pragma unroll
  for (int rt = 0; rt < 4; ++rt) eId[rt] = eSort[e0 + rw*64 + rt*16 + m];

  if (t < 128){
    int e = eSort[e0 + t];
    sIdx[t] = srcI[e]; dIdx[t] = dstI[e];
  }
  __syncthreads();

  // stage PS = PA[src]+PB[dst] into Hs (swizzled), coalesced row reads
  {
    int r = t >> 1, half = t & 1;
    int sr = sIdx[r], dr = dIdx[r];
    #pragma unroll
    for (int j = 0; j < 8; ++j){
      int c8 = half * 8 + j;
      bf16x8 pa = *reinterpret_cast<const bf16x8*>(PA + (size_t)sr * 128 + c8 * 8);
      bf16x8 pb = *reinterpret_cast<const bf16x8*>(PB + (size_t)dr * 128 + c8 * 8);
      bf16x8 ps;
      #pragma unroll
      for (int k = 0; k < 8; ++k) ps[k] = (__bf16)((float)pa[k] + (float)pb[k]);
      int byte = (r * 256 + c8 * 16) ^ ((r & 7) << 4);
      *reinterpret_cast<bf16x8*>(&Hs[byte]) = ps;
    }
  }

  // EA GEMM: K = 64
  const f32x4 FZ = {0.f,0.f,0.f,0.f};
  f32x4 acc[4][4];
  #pragma unroll
  for (int i = 0; i < 4; ++i)
    #pragma unroll
    for (int j = 0; j < 4; ++j) acc[i][j] = FZ;

  #pragma unroll
  for (int ks = 0; ks < 2; ++ks){
    bf16x8 af[4], bfr[4];
    #pragma unroll
    for (int rt = 0; rt < 4; ++rt){
      size_t eb = (size_t)eId[rt] * 64 + ks * 32 + g * 8;
      if (F){
        float4 u0 = *reinterpret_cast<const float4*>(EAf + eb);
        float4 u1 = *reinterpret_cast<const float4*>(EAf + eb + 4);
        bf16x8 v;
        v[0]=(__bf16)u0.x; v[1]=(__bf16)u0.y; v[2]=(__bf16)u0.z; v[3]=(__bf16)u0.w;
        v[4]=(__bf16)u1.x; v[5]=(__bf16)u1.y; v[6]=(__bf16)u1.z; v[7]=(__bf16)u1.w;
        af[rt] = v;
      } else {
        af[rt] = *reinterpret_cast<const bf16x8*>(EAb + eb);
      }
    }
    #pragma unroll
    for (int ct = 0; ct < 4; ++ct){
      int col = cw * 64 + ct * 16 + m;
      bfr[ct] = *reinterpret_cast<const bf16x8*>(W1cT + (size_t)col * 64 + ks * 32 + g * 8);
    }
    #pragma unroll
    for (int rt = 0; rt < 4; ++rt)
      #pragma unroll
      for (int ct = 0; ct < 4; ++ct)
        acc[rt][ct] = MFMA16(af[rt], bfr[ct], acc[rt][ct]);
  }
  __syncthreads();   // PS staged & visible

  // acc += PS + b1
  #pragma unroll
  for (int ct = 0; ct < 4; ++ct){
    int col = cw * 64 + ct * 16 + m;
    float bb = bf2f(SB[col]);
    #pragma unroll
    for (int rt = 0; rt < 4; ++rt)
      #pragma unroll
      for (int r = 0; r < 4; ++r){
        int row = rw * 64 + rt * 16 + g * 4 + r;
        int byte = (row * 256 + col * 2) ^ ((row & 7) << 4);
        acc[rt][ct][r] += bf2f(*reinterpret_cast<const ushort*>(&Hs[byte])) + bb;
      }
  }
  __syncthreads();   // all PS reads done before overwrite

  // gelu -> G into Hs
  #pragma unroll
  for (int ct = 0; ct < 4; ++ct){
    int col = cw * 64 + ct * 16 + m;
    #pragma unroll
    for (int rt = 0; rt < 4; ++rt)
      #pragma unroll
      for (int r = 0; r < 4; ++r){
        int row = rw * 64 + rt * 16 + g * 4 + r;
        int byte = (row * 256 + col * 2) ^ ((row & 7) << 4);
        *reinterpret_cast<ushort*>(&Hs[byte]) = f2bf(gelu_tanh(acc[rt][ct][r]));
      }
  }
  __syncthreads();

  // segmented reduction over dst-sorted rows
  int c = t & 127, hh = t >> 7;
  int rS = hh * 64, rE = rS + 64;
  float run = 0.f;
  int cur = dIdx[rS];
  for (int r = rS; r < rE; ++r){
    int d = dIdx[r];
    if (d != cur){
      unsafeAtomicAdd(&Gagg[(size_t)cur * 128 + c], run);
      run = 0.f; cur = d;
    }
    int byte = (r * 256 + c * 2) ^ ((r & 7) << 4);
    run += bf2f(*reinterpret_cast<const ushort*>(&Hs[byte]));
  }
  unsafeAtomicAdd(&Gagg[(size_t)cur * 128 + c], run);
}

// ---------------- generic node GEMM (used for h_in -> T1 with gelu) ----------------
template<int K, int MODE>   // MODE 1: +bias, gelu -> bf16
__global__ __launch_bounds__(256) void k_gemm(
    const ushort* __restrict__ A, const ushort* __restrict__ WT,
    const ushort* __restrict__ bias, void* __restrict__ out, int M)
{
  int t = threadIdx.x;
  int l = t & 63, w = t >> 6;
  int m = l & 15, g = l >> 4;
  int row0 = blockIdx.x * 64 + w * 16;
  const f32x4 FZ = {0.f,0.f,0.f,0.f};
  f32x4 acc[8];
  #pragma unroll
  for (int i = 0; i < 8; ++i) acc[i] = FZ;

  int arow = row0 + m; if (arow >= M) arow = M - 1;
  #pragma unroll
  for (int ks = 0; ks < K / 32; ++ks){
    int koff = ks * 32 + g * 8;
    bf16x8 a = *reinterpret_cast<const bf16x8*>(A + (size_t)arow * K + koff);
    #pragma unroll
    for (int nt = 0; nt < 8; ++nt){
      bf16x8 b = *reinterpret_cast<const bf16x8*>(WT + (size_t)(nt * 16 + m) * K + koff);
      acc[nt] = MFMA16(a, b, acc[nt]);
    }
  }
  #pragma unroll
  for (int nt = 0; nt < 8; ++nt){
    int col = nt * 16 + m;
    float bb = bf2f(bias[col]);
    #pragma unroll
    for (int r = 0; r < 4; ++r){
      int row = row0 + g * 4 + r;
      if (row < M){
        float v = acc[nt][r] + bb;
        if (MODE == 1) v = gelu_erf(v);
        ((ushort*)out)[(size_t)row * 128 + col] = f2bf(v);
      }
    }
  }
}

// ---------------- attention logits at last-edges (+ global max via block reduce) ----------------
__global__ __launch_bounds__(256) void k_attn(
    const ushort* __restrict__ Qb, const ushort* __restrict__ KV1,
    const ushort* __restrict__ EAb, const float* __restrict__ EAf,
    const ushort* __restrict__ KVW2,
    const int* __restrict__ srcI, const int* __restrict__ last,
    float* __restrict__ attn, uint* __restrict__ Menc, const int* __restrict__ flag)
{
  __shared__ float ea_s[16][64];
  __shared__ int eN[16], sN[16];
  __shared__ uint lmax[8];
  int t = threadIdx.x;
  int n0 = blockIdx.x * 16;
  if (t < 16){
    int e = last[n0 + t];
    eN[t] = e;
    sN[t] = (e >= 0) ? srcI[e] : 0;
  }
  if (t < 8) lmax[t] = 0u;
  __syncthreads();
  int F = *flag;
  for (int i = t; i < 1024; i += 256){
    int nn = i >> 6, k = i & 63;
    int e = eN[nn];
    int ee = (e >= 0) ? e : 0;
    float v = F ? EAf[(size_t)ee * 64 + k] : bf2f(EAb[(size_t)ee * 64 + k]);
    ea_s[nn][k] = (e >= 0) ? v : 0.0f;
  }
  __syncthreads();

  int j = t & 127;
  int half = t >> 7;
  float acc[8];
  #pragma unroll
  for (int i = 0; i < 8; ++i) acc[i] = 0.f;
  for (int k = 0; k < 64; ++k){
    float wv = bf2f(KVW2[(size_t)k * 128 + j]);
    #pragma unroll
    for (int nn = 0; nn < 8; ++nn) acc[nn] += ea_s[half * 8 + nn][k] * wv;
  }
  #pragma unroll
  for (int nn = 0; nn < 8; ++nn){
    int nl = half * 8 + nn;
    int n = n0 + nl;
    int e = eN[nl];
    float kvv = acc[nn] + bf2f(KV1[(size_t)sN[nl] * 128 + j]);
    float qv  = bf2f(Qb[(size_t)n * 128 + j]);
    float p = qv * kvv;
    p += __shfl_xor(p, 1); p += __shfl_xor(p, 2);
    p += __shfl_xor(p, 4); p += __shfl_xor(p, 8);
    if ((j & 15) == 0 && e >= 0){
      float v = p * 0.25f;
      attn[(size_t)n * 8 + (j >> 4)] = v;
      atomicMax(&lmax[j >> 4], encf(v));
    }
  }
  __syncthreads();
  if (t < 8 && lmax[t]) atomicMax(&Menc[t], lmax[t]);
}

// ---------------- softmax denominators ----------------
__global__ __launch_bounds__(256) void k_asum(
    const float* __restrict__ attn, const int* __restrict__ last,
    const uint* __restrict__ Menc, float* __restrict__ S)
{
  __shared__ float red[256][8];
  int t = threadIdx.x;
  float M[8];
  #pragma unroll
  for (int h = 0; h < 8; ++h) M[h] = decf(Menc[h]);
  float p[8];
  #pragma unroll
  for (int h = 0; h < 8; ++h) p[h] = 0.f;
  for (int n = blockIdx.x * 256 + t; n < NN; n += gridDim.x * 256){
    if (last[n] >= 0){
      #pragma unroll
      for (int h = 0; h < 8; ++h) p[h] += __expf(attn[(size_t)n * 8 + h] - M[h]);
    }
  }
  #pragma unroll
  for (int h = 0; h < 8; ++h) red[t][h] = p[h];
  __syncthreads();
  for (int s = 128; s > 0; s >>= 1){
    if (t < s){
      #pragma unroll
      for (int h = 0; h < 8; ++h) red[t][h] += red[t + s][h];
    }
    __syncthreads();
  }
  if (t < 8) atomicAdd(&S[t], red[0][t]);
}

// ---------------- agg GEMM + attnw scale + h_in build ----------------
__global__ __launch_bounds__(256) void k_aggmm(
    const float* __restrict__ Gagg, const ushort* __restrict__ W2T,
    const ushort* __restrict__ SB,            // b2 = SB+128
    const int* __restrict__ cnt, const int* __restrict__ last,
    const float* __restrict__ attn, const uint* __restrict__ Menc,
    const float* __restrict__ S,
    const ushort* __restrict__ NFc, ushort* __restrict__ h_in)
{
  int t = threadIdx.x, l = t & 63, w = t >> 6;
  int m = l & 15, g = l >> 4;
  int row0 = blockIdx.x * 64 + w * 16;

  // copy NF -> h_in first half (block covers rows blockIdx*64..+64)
  {
    int rr = blockIdx.x * 64 + (t >> 2);
    int cc = (t & 3) * 32;
    if (rr < NN){
      #pragma unroll
      for (int j = 0; j < 4; ++j){
        bf16x8 v = *reinterpret_cast<const bf16x8*>(NFc + (size_t)rr * 128 + cc + j * 8);
        *reinterpret_cast<bf16x8*>(h_in + (size_t)rr * 256 + cc + j * 8) = v;
      }
    }
  }

  float M[8], Sinv[8];
  #pragma unroll
  for (int h = 0; h < 8; ++h){ M[h] = decf(Menc[h]); Sinv[h] = 1.0f / S[h]; }

  int arow = row0 + m; if (arow >= NN) arow = NN - 1;
  const f32x4 FZ = {0.f,0.f,0.f,0.f};
  f32x4 acc[8];
  #pragma unroll
  for (int i = 0; i < 8; ++i) acc[i] = FZ;

  #pragma unroll
  for (int ks = 0; ks < 4; ++ks){
    const float* gp = Gagg + (size_t)arow * 128 + ks * 32 + g * 8;
    float4 u0 = *reinterpret_cast<const float4*>(gp);
    float4 u1 = *reinterpret_cast<const float4*>(gp + 4);
    float gv[8] = {u0.x,u0.y,u0.z,u0.w,u1.x,u1.y,u1.z,u1.w};
    bf16x8 hi, lo;
    #pragma unroll
    for (int k = 0; k < 8; ++k){
      hi[k] = (__bf16)gv[k];
      lo[k] = (__bf16)(gv[k] - (float)hi[k]);
    }
    #pragma unroll
    for (int nt = 0; nt < 8; ++nt){
      bf16x8 b = *reinterpret_cast<const bf16x8*>(W2T + (size_t)(nt*16+m) * 128 + ks * 32 + g * 8);
      acc[nt] = MFMA16(hi, b, acc[nt]);
      acc[nt] = MFMA16(lo, b, acc[nt]);
    }
  }

  #pragma unroll
  for (int r = 0; r < 4; ++r){
    int row = row0 + g * 4 + r;
    if (row < NN){
      float cn = (float)cnt[row];
      int lst = last[row];
      #pragma unroll
      for (int nt = 0; nt < 8; ++nt){
        int col = nt * 16 + m;
        float bb = bf2f(SB[128 + col]);
        float aw = (lst >= 0) ? __expf(attn[(size_t)row * 8 + nt] - M[nt]) * Sinv[nt] : 0.f;
        float v = (acc[nt][r] + cn * bb) * aw;
        h_in[(size_t)row * 256 + 128 + col] = f2bf(v);
      }
    }
  }
}

// ---------------- final GEMM + residual + LayerNorm ----------------
__global__ __launch_bounds__(256) void k_out2ln(
    const ushort* __restrict__ T1, const ushort* __restrict__ O2T,
    const ushort* __restrict__ SB,    // ob2 = SB+640, ln_g = SB+768, ln_b = SB+896
    const ushort* __restrict__ NFc, void* __restrict__ out,
    const int* __restrict__ flag)
{
  int t = threadIdx.x, l = t & 63, w = t >> 6;
  int m = l & 15, g = l >> 4;
  int row0 = blockIdx.x * 64 + w * 16;
  int F = *flag;
  int arow = row0 + m; if (arow >= NN) arow = NN - 1;
  const f32x4 FZ = {0.f,0.f,0.f,0.f};
  f32x4 acc[8];
  #pragma unroll
  for (int i = 0; i < 8; ++i) acc[i] = FZ;
  #pragma unroll
  for (int ks = 0; ks < 4; ++ks){
    int koff = ks * 32 + g * 8;
    bf16x8 a = *reinterpret_cast<const bf16x8*>(T1 + (size_t)arow * 128 + koff);
    #pragma unroll
    for (int nt = 0; nt < 8; ++nt){
      bf16x8 b = *reinterpret_cast<const bf16x8*>(O2T + (size_t)(nt*16+m) * 128 + koff);
      acc[nt] = MFMA16(a, b, acc[nt]);
    }
  }
  #pragma unroll
  for (int r = 0; r < 4; ++r){
    int row = row0 + g * 4 + r;
    bool ok = row < NN;
    int rr = ok ? row : NN - 1;
    float x[8]; float s = 0.f, q = 0.f;
    #pragma unroll
    for (int nt = 0; nt < 8; ++nt){
      int col = nt * 16 + m;
      float xv = acc[nt][r] + bf2f(SB[640 + col]) + bf2f(NFc[(size_t)rr * 128 + col]);
      x[nt] = xv; s += xv; q += xv * xv;
    }
    #pragma unroll
    for (int msk = 1; msk < 16; msk <<= 1){
      s += __shfl_xor(s, msk);
      q += __shfl_xor(q, msk);
    }
    float mean = s * (1.0f / 128.0f);
    float var  = q * (1.0f / 128.0f) - mean * mean;
    float rs = rsqrtf(var + 1e-5f);
    if (ok){
      #pragma unroll
      for (int nt = 0; nt < 8; ++nt){
        int col = nt * 16 + m;
        float y = (x[nt] - mean) * rs * bf2f(SB[768 + col]) + bf2f(SB[896 + col]);
        if (F) ((float*)out)[(size_t)row * 128 + col] = y;
        else   ((ushort*)out)[(size_t)row * 128 + col] = f2bf(y);
      }
    }
  }
}

// ---------------- host ----------------
extern "C" void kernel_launch(void* const* d_in, const int* in_sizes, int n_in,
                              void* d_out, int out_size, void* d_ws, size_t ws_size,
                              hipStream_t stream)
{
  const void* NF0  = d_in[0];
  const void* EA0  = d_in[1];
  const void* w1   = d_in[2];
  const void* b1   = d_in[3];
  const void* w2   = d_in[4];
  const void* b2   = d_in[5];
  const void* qw   = d_in[6];
  const void* qb   = d_in[7];
  const void* kvw  = d_in[8];
  const void* kvb  = d_in[9];
  const void* ow1  = d_in[10];
  const void* ob1  = d_in[11];
  const void* ow2  = d_in[12];
  const void* ob2  = d_in[13];
  const void* lg   = d_in[14];
  const void* lb   = d_in[15];
  const int*  srcI = (const int*)d_in[16];
  const int*  dstI = srcI + NE;

  char* ws = (char*)d_ws;
  size_t off = 0;
  auto alloc = [&](size_t bytes) -> void* {
    void* p = ws + off;
    off = (off + bytes + 255) & ~(size_t)255;
    return p;
  };
  int*    flag  = (int*)   alloc(4);
  ushort* NFc   = (ushort*)alloc((size_t)NN * 128 * 2);
  ushort* SB    = (ushort*)alloc(8 * 128 * 2);
  ushort* KVW2  = (ushort*)alloc(64 * 128 * 2);
  ushort* W1aT  = (ushort*)alloc(128 * 128 * 2);
  ushort* W1bT  = (ushort*)alloc(128 * 128 * 2);
  ushort* W1cT  = (ushort*)alloc(128 * 64 * 2);
  ushort* W2T   = (ushort*)alloc(128 * 128 * 2);
  ushort* QT    = (ushort*)alloc(128 * 128 * 2);
  ushort* KVT   = (ushort*)alloc(128 * 128 * 2);
  ushort* O1T   = (ushort*)alloc(128 * 256 * 2);
  ushort* O2T   = (ushort*)alloc(128 * 128 * 2);
  int*    last  = (int*)   alloc(NN * 4);
  int*    cnt   = (int*)   alloc(NN * 4);
  int*    fill  = (int*)   alloc(NN * 4);
  int*    eSort = (int*)   alloc((size_t)NE * 4);
  float*  attn  = (float*) alloc(NN * 8 * 4);
  uint*   Menc  = (uint*)  alloc(8 * 4);
  float*  S     = (float*) alloc(8 * 4);
  ushort* PA    = (ushort*)alloc((size_t)NN * 128 * 2);
  ushort* PB    = (ushort*)alloc((size_t)NN * 128 * 2);
  ushort* Qb    = (ushort*)alloc((size_t)NN * 128 * 2);
  ushort* KV1   = (ushort*)alloc((size_t)NN * 128 * 2);
  float*  Gagg  = (float*) alloc((size_t)NN * 128 * 4);
  ushort* h_in  = (ushort*)alloc((size_t)NN * 256 * 2);
  ushort* T1    = (ushort*)alloc((size_t)NN * 128 * 2);

  k_detect<<<1, 256, 0, stream>>>((const uint*)NF0, flag);
  k_prep<<<3159, 256, 0, stream>>>(NF0, w1, w2, qw, kvw, ow1, ow2,
                                   b1, b2, qb, kvb, ob1, ob2, lg, lb,
                                   NFc, Gagg, last, cnt, Menc, S, SB, KVW2,
                                   W1aT, W1bT, W1cT, W2T, QT, KVT, O1T, O2T, flag);
  k_count<<<1250, 256, 0, stream>>>(dstI, cnt, last);
  k_scan<<<1, 1024, 0, stream>>>(cnt, fill);
  k_fill<<<1250, 256, 0, stream>>>(dstI, fill, eSort);
  k_nodepack<<<625, 256, 0, stream>>>(NFc, W1aT, W1bT, QT, KVT, SB, PA, PB, Qb, KV1);
  k_edge<<<2500, 256, 0, stream>>>(PA, PB, (const float*)EA0, (const ushort*)EA0,
                                   srcI, dstI, eSort, W1cT, SB, Gagg, flag);
  k_attn<<<625, 256, 0, stream>>>(Qb, KV1, (const ushort*)EA0, (const float*)EA0,
                                  KVW2, srcI, last, attn, Menc, flag);
  k_asum<<<40, 256, 0, stream>>>(attn, last, Menc, S);
  k_aggmm<<<157, 256, 0, stream>>>(Gagg, W2T, SB, cnt, last, attn, Menc, S, NFc, h_in);
  k_gemm<256, 1><<<157, 256, 0, stream>>>(h_in, O1T, SB + 512, T1, NN);
  k_out2ln<<<157, 256, 0, stream>>>(T1, O2T, SB, NFc, d_out, flag);
}

// Round 5
// 240.681 us; speedup vs baseline: 1.8147x; 1.1019x over previous
//
#include <hip/hip_runtime.h>
#include <hip/hip_bf16.h>

#define NN 10000
#define NE 320000

typedef __bf16 bf16x8 __attribute__((ext_vector_type(8)));
typedef float  f32x4  __attribute__((ext_vector_type(4)));

__device__ __forceinline__ float bf2f(ushort u){
  union { uint i; float f; } c; c.i = ((uint)u) << 16; return c.f;
}
__device__ __forceinline__ ushort f2bf(float f){
  union { float f; uint i; } c; c.f = f;
  uint x = c.i;
  return (ushort)((x + 0x7FFFu + ((x >> 16) & 1u)) >> 16);
}
__device__ __forceinline__ float gelu_erf(float x){
  return 0.5f * x * (1.0f + erff(x * 0.70710678118654752f));
}
__device__ __forceinline__ float gelu_tanh(float x){
  float y = 0.7978845608028654f * (x + 0.044715f * x * x * x);
  float e = __expf(2.f * y);
  float th = 1.f - 2.f / (e + 1.f);
  return 0.5f * x * (1.f + th);
}
__device__ __forceinline__ uint encf(float f){
  uint u = __float_as_uint(f);
  return (u & 0x80000000u) ? ~u : (u | 0x80000000u);
}
__device__ __forceinline__ float decf(uint u){
  return __uint_as_float((u & 0x80000000u) ? (u & 0x7FFFFFFFu) : ~u);
}
#define MFMA16(a,b,c) __builtin_amdgcn_mfma_f32_16x16x32_bf16((a),(b),(c),0,0,0)

// ---------------- dtype detection: flag=1 -> inputs are fp32 ----------------
__global__ void k_detect(const uint* __restrict__ w, int* __restrict__ flag){
  int t = threadIdx.x;
  uint cnt = 0;
  for (int i = t; i < 4096; i += 256){
    uint v = w[i * 63];
    uint e = (v >> 7) & 0xFF;
    if (e >= 100 && e <= 140) cnt++;
  }
  __shared__ uint red[256];
  red[t] = cnt; __syncthreads();
  for (int s = 128; s > 0; s >>= 1){
    if (t < s) red[t] += red[t + s];
    __syncthreads();
  }
  if (t == 0) *flag = (red[0] < 2048) ? 1 : 0;
}

// ---------------- one-shot prep: cvt + zeros + all weight transposes ----------------
__global__ void k_prep(
    const void* NF0, const void* w1, const void* w2, const void* qw, const void* kvw,
    const void* ow1, const void* ow2,
    const void* b1, const void* b2, const void* qb, const void* kvb,
    const void* ob1, const void* ob2, const void* lg, const void* lb,
    ushort* NFc, float* Gagg, int* last, int* cnt, uint* Menc, float* S,
    ushort* SB, ushort* KVW2,
    ushort* W1aT, ushort* W1bT, ushort* W1cT, ushort* W2T, ushort* QT, ushort* KVT,
    ushort* O1T, ushort* O2T, const int* flag)
{
  int f = *flag;
  int idx = blockIdx.x * 256 + threadIdx.x;
  if (idx < 320000){
    if (f){
      float4 v = ((const float4*)NF0)[idx];
      ushort4 o; o.x=f2bf(v.x); o.y=f2bf(v.y); o.z=f2bf(v.z); o.w=f2bf(v.w);
      ((ushort4*)NFc)[idx] = o;
    } else ((ushort4*)NFc)[idx] = ((const ushort4*)NF0)[idx];
    return;
  }
  idx -= 320000;
  if (idx < 320000){ float4 z = {0.f,0.f,0.f,0.f}; ((float4*)Gagg)[idx] = z; return; }
  idx -= 320000;
  if (idx < 20016){
    if (idx < 10000) last[idx] = -1;
    else if (idx < 20000) cnt[idx - 10000] = 0;
    else if (idx < 20008) Menc[idx - 20000] = 0u;
    else S[idx - 20008] = 0.f;
    return;
  }
  idx -= 20016;
  if (idx < 1024){
    const void* ps[8] = {b1,b2,qb,kvb,ob1,ob2,lg,lb};
    const void* p = ps[idx >> 7]; int j = idx & 127;
    SB[idx] = f ? f2bf(((const float*)p)[j]) : ((const ushort*)p)[j];
    return;
  }
  idx -= 1024;
  if (idx < 8192){
    KVW2[idx] = f ? f2bf(((const float*)kvw)[16384 + idx]) : ((const ushort*)kvw)[16384 + idx];
    return;
  }
  idx -= 8192;
  if (idx < 16384){ int c=idx>>7,k=idx&127; W1aT[idx] = f? f2bf(((const float*)w1)[k*128+c]) : ((const ushort*)w1)[k*128+c]; return; }
  idx -= 16384;
  if (idx < 16384){ int c=idx>>7,k=idx&127; W1bT[idx] = f? f2bf(((const float*)w1)[(128+k)*128+c]) : ((const ushort*)w1)[(128+k)*128+c]; return; }
  idx -= 16384;
  if (idx < 8192){ int c=idx>>6,k=idx&63;  W1cT[idx] = f? f2bf(((const float*)w1)[(256+k)*128+c]) : ((const ushort*)w1)[(256+k)*128+c]; return; }
  idx -= 8192;
  if (idx < 16384){ int c=idx>>7,k=idx&127; W2T[idx] = f? f2bf(((const float*)w2)[k*128+c]) : ((const ushort*)w2)[k*128+c]; return; }
  idx -= 16384;
  if (idx < 16384){ int c=idx>>7,k=idx&127; QT[idx]  = f? f2bf(((const float*)qw)[k*128+c]) : ((const ushort*)qw)[k*128+c]; return; }
  idx -= 16384;
  if (idx < 16384){ int c=idx>>7,k=idx&127; KVT[idx] = f? f2bf(((const float*)kvw)[k*128+c]) : ((const ushort*)kvw)[k*128+c]; return; }
  idx -= 16384;
  if (idx < 32768){ int c=idx>>8,k=idx&255; O1T[idx] = f? f2bf(((const float*)ow1)[k*128+c]) : ((const ushort*)ow1)[k*128+c]; return; }
  idx -= 32768;
  if (idx < 16384){ int c=idx>>7,k=idx&127; O2T[idx] = f? f2bf(((const float*)ow2)[k*128+c]) : ((const ushort*)ow2)[k*128+c]; return; }
}

// ---------------- CSR build ----------------
__global__ void k_count(const int* __restrict__ dst, int* __restrict__ cnt,
                        int* __restrict__ last){
  int e = blockIdx.x * 256 + threadIdx.x;
  if (e < NE){
    int d = dst[e];
    atomicAdd(&cnt[d], 1);
    atomicMax(&last[d], e);
  }
}

__global__ __launch_bounds__(1024) void k_scan(const int* __restrict__ cnt,
                                               int* __restrict__ fill){
  __shared__ int sc[1024];
  int t = threadIdx.x;
  int base = t * 10;
  int v[10]; int tot = 0;
  #pragma unroll
  for (int j = 0; j < 10; ++j){
    int idx = base + j;
    v[j] = (idx < NN) ? cnt[idx] : 0;
    tot += v[j];
  }
  sc[t] = tot; __syncthreads();
  for (int off = 1; off < 1024; off <<= 1){
    int x = (t >= off) ? sc[t - off] : 0;
    __syncthreads();
    sc[t] += x;
    __syncthreads();
  }
  int run = sc[t] - tot;   // exclusive
  #pragma unroll
  for (int j = 0; j < 10; ++j){
    int idx = base + j;
    if (idx < NN) fill[idx] = run;
    run += v[j];
  }
}

// fill: pos (inverse perm) + sorted src/dst arrays
__global__ void k_fill(const int* __restrict__ src, const int* __restrict__ dst,
                       int* __restrict__ fill, int* __restrict__ pos,
                       int* __restrict__ sSort, int* __restrict__ dSort){
  int e = blockIdx.x * 256 + threadIdx.x;
  if (e < NE){
    int d = dst[e];
    int p = atomicAdd(&fill[d], 1);
    pos[e] = p;
    sSort[p] = src[e];
    dSort[p] = d;
  }
}

// ---------------- permute EA into dst-sorted order (coalesced read, scatter write) ----------------
__global__ __launch_bounds__(256) void k_perm(
    const float* __restrict__ EAf, const ushort* __restrict__ EAb,
    const int* __restrict__ pos, ushort* __restrict__ EAs,
    const int* __restrict__ flag)
{
  int i = blockIdx.x * 256 + threadIdx.x;   // [0, 2*NE)
  int r = i >> 1, half = i & 1;
  if (r >= NE) return;
  int p = pos[r];
  ushort* op = EAs + (size_t)p * 64 + half * 32;
  if (*flag){
    const float* in = EAf + (size_t)r * 64 + half * 32;
    #pragma unroll
    for (int j = 0; j < 4; ++j){
      float4 a = *reinterpret_cast<const float4*>(in + j * 8);
      float4 b = *reinterpret_cast<const float4*>(in + j * 8 + 4);
      bf16x8 v;
      v[0]=(__bf16)a.x; v[1]=(__bf16)a.y; v[2]=(__bf16)a.z; v[3]=(__bf16)a.w;
      v[4]=(__bf16)b.x; v[5]=(__bf16)b.y; v[6]=(__bf16)b.z; v[7]=(__bf16)b.w;
      *reinterpret_cast<bf16x8*>(op + j * 8) = v;
    }
  } else {
    const ushort* in = EAb + (size_t)r * 64 + half * 32;
    #pragma unroll
    for (int j = 0; j < 4; ++j)
      *reinterpret_cast<bf16x8*>(op + j * 8) =
        *reinterpret_cast<const bf16x8*>(in + j * 8);
  }
}

// ---------------- fused node pre-GEMMs: PA,PB(+b1),Qb,KV1 ----------------
__global__ __launch_bounds__(256) void k_nodepack(
    const ushort* __restrict__ NFc,
    const ushort* __restrict__ W1aT, const ushort* __restrict__ W1bT,
    const ushort* __restrict__ QT,  const ushort* __restrict__ KVT,
    const ushort* __restrict__ SB,
    ushort* __restrict__ PA, ushort* __restrict__ PB,
    ushort* __restrict__ Qb, ushort* __restrict__ KV1)
{
  int t = threadIdx.x, l = t & 63, w = t >> 6;
  int m = l & 15, g = l >> 4;
  int row0 = blockIdx.x * 16;
  const ushort* WT = (w==0) ? W1aT : (w==1) ? W1bT : (w==2) ? QT : KVT;
  ushort*       OUT= (w==0) ? PA   : (w==1) ? PB   : (w==2) ? Qb : KV1;
  const f32x4 FZ = {0.f,0.f,0.f,0.f};
  f32x4 acc[8];
  #pragma unroll
  for (int i = 0; i < 8; ++i) acc[i] = FZ;
  int arow = row0 + m;
  #pragma unroll
  for (int ks = 0; ks < 4; ++ks){
    int koff = ks * 32 + g * 8;
    bf16x8 a = *reinterpret_cast<const bf16x8*>(NFc + (size_t)arow * 128 + koff);
    #pragma unroll
    for (int nt = 0; nt < 8; ++nt){
      bf16x8 b = *reinterpret_cast<const bf16x8*>(WT + (size_t)(nt*16+m) * 128 + koff);
      acc[nt] = MFMA16(a, b, acc[nt]);
    }
  }
  #pragma unroll
  for (int nt = 0; nt < 8; ++nt){
    int col = nt * 16 + m;
    float bb = (w==1) ? bf2f(SB[col]) : (w==2) ? bf2f(SB[256+col]) : (w==3) ? bf2f(SB[384+col]) : 0.f;
    #pragma unroll
    for (int r = 0; r < 4; ++r){
      int row = row0 + g * 4 + r;
      OUT[(size_t)row * 128 + col] = f2bf(acc[nt][r] + bb);
    }
  }
}

// ---------------- edge kernel: all-coalesced; pre=PS+EAs@W1c -> gelu -> seg-reduce ----------------
__global__ __launch_bounds__(256) void k_edge(
    const ushort* __restrict__ PA, const ushort* __restrict__ PB,
    const ushort* __restrict__ EAs,
    const int* __restrict__ sSort, const int* __restrict__ dSort,
    const ushort* __restrict__ W1cT,
    float* __restrict__ Gagg)
{
  __shared__ int sIdx[128], dIdx[128];
  __shared__ __align__(16) char Hs[128 * 256];   // PS, then G (bf16, XOR-swizzled)
  int t = threadIdx.x;
  int p0 = blockIdx.x * 128;
  int l = t & 63, w = t >> 6;
  int rw = w >> 1, cw = w & 1;
  int m = l & 15, g = l >> 4;

  if (t < 128){ sIdx[t] = sSort[p0 + t]; dIdx[t] = dSort[p0 + t]; }
  __syncthreads();

  // stage PS = PA[src]+PB[dst] (b1 already folded into PB)
  {
    int r = t >> 1, half = t & 1;
    int sr = sIdx[r], dr = dIdx[r];
    #pragma unroll
    for (int j = 0; j < 8; ++j){
      int c8 = half * 8 + j;
      bf16x8 pa = *reinterpret_cast<const bf16x8*>(PA + (size_t)sr * 128 + c8 * 8);
      bf16x8 pb = *reinterpret_cast<const bf16x8*>(PB + (size_t)dr * 128 + c8 * 8);
      bf16x8 ps;
      #pragma unroll
      for (int k = 0; k < 8; ++k) ps[k] = (__bf16)((float)pa[k] + (float)pb[k]);
      int byte = (r * 256 + c8 * 16) ^ ((r & 7) << 4);
      *reinterpret_cast<bf16x8*>(&Hs[byte]) = ps;
    }
  }

  // EA GEMM: K = 64, fully coalesced A reads (sorted order)
  const f32x4 FZ = {0.f,0.f,0.f,0.f};
  f32x4 acc[4][4];
  #pragma unroll
  for (int i = 0; i < 4; ++i)
    #pragma unroll
    for (int j = 0; j < 4; ++j) acc[i][j] = FZ;

  #pragma unroll
  for (int ks = 0; ks < 2; ++ks){
    bf16x8 af[4], bfr[4];
    #pragma unroll
    for (int rt = 0; rt < 4; ++rt){
      int rl = rw * 64 + rt * 16 + m;
      af[rt] = *reinterpret_cast<const bf16x8*>(EAs + (size_t)(p0 + rl) * 64 + ks * 32 + g * 8);
    }
    #pragma unroll
    for (int ct = 0; ct < 4; ++ct){
      int col = cw * 64 + ct * 16 + m;
      bfr[ct] = *reinterpret_cast<const bf16x8*>(W1cT + (size_t)col * 64 + ks * 32 + g * 8);
    }
    #pragma unroll
    for (int rt = 0; rt < 4; ++rt)
      #pragma unroll
      for (int ct = 0; ct < 4; ++ct)
        acc[rt][ct] = MFMA16(af[rt], bfr[ct], acc[rt][ct]);
  }
  __syncthreads();   // PS staged & visible

  // fused: G = gelu(acc + PS); write back to same LDS slot (same-thread RMW, safe)
  #pragma unroll
  for (int ct = 0; ct < 4; ++ct){
    int col = cw * 64 + ct * 16 + m;
    #pragma unroll
    for (int rt = 0; rt < 4; ++rt)
      #pragma unroll
      for (int r = 0; r < 4; ++r){
        int row = rw * 64 + rt * 16 + g * 4 + r;
        int byte = (row * 256 + col * 2) ^ ((row & 7) << 4);
        float v = gelu_tanh(acc[rt][ct][r] + bf2f(*reinterpret_cast<const ushort*>(&Hs[byte])));
        *reinterpret_cast<ushort*>(&Hs[byte]) = f2bf(v);
      }
  }
  __syncthreads();

  // segmented reduction over dst-sorted rows (wave-uniform boundaries)
  int c = t & 127, hh = t >> 7;
  int rS = hh * 64, rE = rS + 64;
  float run = 0.f;
  int cur = dIdx[rS];
  for (int r = rS; r < rE; ++r){
    int d = dIdx[r];
    if (d != cur){
      unsafeAtomicAdd(&Gagg[(size_t)cur * 128 + c], run);
      run = 0.f; cur = d;
    }
    int byte = (r * 256 + c * 2) ^ ((r & 7) << 4);
    run += bf2f(*reinterpret_cast<const ushort*>(&Hs[byte]));
  }
  unsafeAtomicAdd(&Gagg[(size_t)cur * 128 + c], run);
}

// ---------------- generic node GEMM (h_in -> T1 with gelu) ----------------
template<int K, int MODE>
__global__ __launch_bounds__(256) void k_gemm(
    const ushort* __restrict__ A, const ushort* __restrict__ WT,
    const ushort* __restrict__ bias, void* __restrict__ out, int M)
{
  int t = threadIdx.x;
  int l = t & 63, w = t >> 6;
  int m = l & 15, g = l >> 4;
  int row0 = blockIdx.x * 64 + w * 16;
  const f32x4 FZ = {0.f,0.f,0.f,0.f};
  f32x4 acc[8];
  #pragma unroll
  for (int i = 0; i < 8; ++i) acc[i] = FZ;

  int arow = row0 + m; if (arow >= M) arow = M - 1;
  #pragma unroll
  for (int ks = 0; ks < K / 32; ++ks){
    int koff = ks * 32 + g * 8;
    bf16x8 a = *reinterpret_cast<const bf16x8*>(A + (size_t)arow * K + koff);
    #pragma unroll
    for (int nt = 0; nt < 8; ++nt){
      bf16x8 b = *reinterpret_cast<const bf16x8*>(WT + (size_t)(nt * 16 + m) * K + koff);
      acc[nt] = MFMA16(a, b, acc[nt]);
    }
  }
  #pragma unroll
  for (int nt = 0; nt < 8; ++nt){
    int col = nt * 16 + m;
    float bb = bf2f(bias[col]);
    #pragma unroll
    for (int r = 0; r < 4; ++r){
      int row = row0 + g * 4 + r;
      if (row < M){
        float v = acc[nt][r] + bb;
        if (MODE == 1) v = gelu_erf(v);
        ((ushort*)out)[(size_t)row * 128 + col] = f2bf(v);
      }
    }
  }
}

// ---------------- attention logits at last-edges (+ global max) ----------------
__global__ __launch_bounds__(256) void k_attn(
    const ushort* __restrict__ Qb, const ushort* __restrict__ KV1,
    const ushort* __restrict__ EAb, const float* __restrict__ EAf,
    const ushort* __restrict__ KVW2,
    const int* __restrict__ srcI, const int* __restrict__ last,
    float* __restrict__ attn, uint* __restrict__ Menc, const int* __restrict__ flag)
{
  __shared__ float ea_s[16][64];
  __shared__ int eN[16], sN[16];
  __shared__ uint lmax[8];
  int t = threadIdx.x;
  int n0 = blockIdx.x * 16;
  if (t < 16){
    int e = last[n0 + t];
    eN[t] = e;
    sN[t] = (e >= 0) ? srcI[e] : 0;
  }
  if (t < 8) lmax[t] = 0u;
  __syncthreads();
  int F = *flag;
  for (int i = t; i < 1024; i += 256){
    int nn = i >> 6, k = i & 63;
    int e = eN[nn];
    int ee = (e >= 0) ? e : 0;
    float v = F ? EAf[(size_t)ee * 64 + k] : bf2f(EAb[(size_t)ee * 64 + k]);
    ea_s[nn][k] = (e >= 0) ? v : 0.0f;
  }
  __syncthreads();

  int j = t & 127;
  int half = t >> 7;
  float acc[8];
  #pragma unroll
  for (int i = 0; i < 8; ++i) acc[i] = 0.f;
  for (int k = 0; k < 64; ++k){
    float wv = bf2f(KVW2[(size_t)k * 128 + j]);
    #pragma unroll
    for (int nn = 0; nn < 8; ++nn) acc[nn] += ea_s[half * 8 + nn][k] * wv;
  }
  #pragma unroll
  for (int nn = 0; nn < 8; ++nn){
    int nl = half * 8 + nn;
    int n = n0 + nl;
    int e = eN[nl];
    float kvv = acc[nn] + bf2f(KV1[(size_t)sN[nl] * 128 + j]);
    float qv  = bf2f(Qb[(size_t)n * 128 + j]);
    float p = qv * kvv;
    p += __shfl_xor(p, 1); p += __shfl_xor(p, 2);
    p += __shfl_xor(p, 4); p += __shfl_xor(p, 8);
    if ((j & 15) == 0 && e >= 0){
      float v = p * 0.25f;
      attn[(size_t)n * 8 + (j >> 4)] = v;
      atomicMax(&lmax[j >> 4], encf(v));
    }
  }
  __syncthreads();
  if (t < 8 && lmax[t]) atomicMax(&Menc[t], lmax[t]);
}

// ---------------- softmax denominators ----------------
__global__ __launch_bounds__(256) void k_asum(
    const float* __restrict__ attn, const int* __restrict__ last,
    const uint* __restrict__ Menc, float* __restrict__ S)
{
  __shared__ float red[256][8];
  int t = threadIdx.x;
  float M[8];
  #pragma unroll
  for (int h = 0; h < 8; ++h) M[h] = decf(Menc[h]);
  float p[8];
  #pragma unroll
  for (int h = 0; h < 8; ++h) p[h] = 0.f;
  for (int n = blockIdx.x * 256 + t; n < NN; n += gridDim.x * 256){
    if (last[n] >= 0){
      #pragma unroll
      for (int h = 0; h < 8; ++h) p[h] += __expf(attn[(size_t)n * 8 + h] - M[h]);
    }
  }
  #pragma unroll
  for (int h = 0; h < 8; ++h) red[t][h] = p[h];
  __syncthreads();
  for (int s = 128; s > 0; s >>= 1){
    if (t < s){
      #pragma unroll
      for (int h = 0; h < 8; ++h) red[t][h] += red[t + s][h];
    }
    __syncthreads();
  }
  if (t < 8) atomicAdd(&S[t], red[0][t]);
}

// ---------------- agg GEMM + attnw scale + h_in build ----------------
__global__ __launch_bounds__(256) void k_aggmm(
    const float* __restrict__ Gagg, const ushort* __restrict__ W2T,
    const ushort* __restrict__ SB,
    const int* __restrict__ cnt, const int* __restrict__ last,
    const float* __restrict__ attn, const uint* __restrict__ Menc,
    const float* __restrict__ S,
    const ushort* __restrict__ NFc, ushort* __restrict__ h_in)
{
  int t = threadIdx.x, l = t & 63, w = t >> 6;
  int m = l & 15, g = l >> 4;
  int row0 = blockIdx.x * 64 + w * 16;

  {
    int rr = blockIdx.x * 64 + (t >> 2);
    int cc = (t & 3) * 32;
    if (rr < NN){
      #pragma unroll
      for (int j = 0; j < 4; ++j){
        bf16x8 v = *reinterpret_cast<const bf16x8*>(NFc + (size_t)rr * 128 + cc + j * 8);
        *reinterpret_cast<bf16x8*>(h_in + (size_t)rr * 256 + cc + j * 8) = v;
      }
    }
  }

  float M[8], Sinv[8];
  #pragma unroll
  for (int h = 0; h < 8; ++h){ M[h] = decf(Menc[h]); Sinv[h] = 1.0f / S[h]; }

  int arow = row0 + m; if (arow >= NN) arow = NN - 1;
  const f32x4 FZ = {0.f,0.f,0.f,0.f};
  f32x4 acc[8];
  #pragma unroll
  for (int i = 0; i < 8; ++i) acc[i] = FZ;

  #pragma unroll
  for (int ks = 0; ks < 4; ++ks){
    const float* gp = Gagg + (size_t)arow * 128 + ks * 32 + g * 8;
    float4 u0 = *reinterpret_cast<const float4*>(gp);
    float4 u1 = *reinterpret_cast<const float4*>(gp + 4);
    float gv[8] = {u0.x,u0.y,u0.z,u0.w,u1.x,u1.y,u1.z,u1.w};
    bf16x8 hi, lo;
    #pragma unroll
    for (int k = 0; k < 8; ++k){
      hi[k] = (__bf16)gv[k];
      lo[k] = (__bf16)(gv[k] - (float)hi[k]);
    }
    #pragma unroll
    for (int nt = 0; nt < 8; ++nt){
      bf16x8 b = *reinterpret_cast<const bf16x8*>(W2T + (size_t)(nt*16+m) * 128 + ks * 32 + g * 8);
      acc[nt] = MFMA16(hi, b, acc[nt]);
      acc[nt] = MFMA16(lo, b, acc[nt]);
    }
  }

  #pragma unroll
  for (int r = 0; r < 4; ++r){
    int row = row0 + g * 4 + r;
    if (row < NN){
      float cn = (float)cnt[row];
      int lst = last[row];
      #pragma unroll
      for (int nt = 0; nt < 8; ++nt){
        int col = nt * 16 + m;
        float bb = bf2f(SB[128 + col]);
        float aw = (lst >= 0) ? __expf(attn[(size_t)row * 8 + nt] - M[nt]) * Sinv[nt] : 0.f;
        float v = (acc[nt][r] + cn * bb) * aw;
        h_in[(size_t)row * 256 + 128 + col] = f2bf(v);
      }
    }
  }
}

// ---------------- final GEMM + residual + LayerNorm ----------------
__global__ __launch_bounds__(256) void k_out2ln(
    const ushort* __restrict__ T1, const ushort* __restrict__ O2T,
    const ushort* __restrict__ SB,
    const ushort* __restrict__ NFc, void* __restrict__ out,
    const int* __restrict__ flag)
{
  int t = threadIdx.x, l = t & 63, w = t >> 6;
  int m = l & 15, g = l >> 4;
  int row0 = blockIdx.x * 64 + w * 16;
  int F = *flag;
  int arow = row0 + m; if (arow >= NN) arow = NN - 1;
  const f32x4 FZ = {0.f,0.f,0.f,0.f};
  f32x4 acc[8];
  #pragma unroll
  for (int i = 0; i < 8; ++i) acc[i] = FZ;
  #pragma unroll
  for (int ks = 0; ks < 4; ++ks){
    int koff = ks * 32 + g * 8;
    bf16x8 a = *reinterpret_cast<const bf16x8*>(T1 + (size_t)arow * 128 + koff);
    #pragma unroll
    for (int nt = 0; nt < 8; ++nt){
      bf16x8 b = *reinterpret_cast<const bf16x8*>(O2T + (size_t)(nt*16+m) * 128 + koff);
      acc[nt] = MFMA16(a, b, acc[nt]);
    }
  }
  #pragma unroll
  for (int r = 0; r < 4; ++r){
    int row = row0 + g * 4 + r;
    bool ok = row < NN;
    int rr = ok ? row : NN - 1;
    float x[8]; float s = 0.f, q = 0.f;
    #pragma unroll
    for (int nt = 0; nt < 8; ++nt){
      int col = nt * 16 + m;
      float xv = acc[nt][r] + bf2f(SB[640 + col]) + bf2f(NFc[(size_t)rr * 128 + col]);
      x[nt] = xv; s += xv; q += xv * xv;
    }
    #pragma unroll
    for (int msk = 1; msk < 16; msk <<= 1){
      s += __shfl_xor(s, msk);
      q += __shfl_xor(q, msk);
    }
    float mean = s * (1.0f / 128.0f);
    float var  = q * (1.0f / 128.0f) - mean * mean;
    float rs = rsqrtf(var + 1e-5f);
    if (ok){
      #pragma unroll
      for (int nt = 0; nt < 8; ++nt){
        int col = nt * 16 + m;
        float y = (x[nt] - mean) * rs * bf2f(SB[768 + col]) + bf2f(SB[896 + col]);
        if (F) ((float*)out)[(size_t)row * 128 + col] = y;
        else   ((ushort*)out)[(size_t)row * 128 + col] = f2bf(y);
      }
    }
  }
}

// ---------------- host ----------------
extern "C" void kernel_launch(void* const* d_in, const int* in_sizes, int n_in,
                              void* d_out, int out_size, void* d_ws, size_t ws_size,
                              hipStream_t stream)
{
  const void* NF0  = d_in[0];
  const void* EA0  = d_in[1];
  const void* w1   = d_in[2];
  const void* b1   = d_in[3];
  const void* w2   = d_in[4];
  const void* b2   = d_in[5];
  const void* qw   = d_in[6];
  const void* qb   = d_in[7];
  const void* kvw  = d_in[8];
  const void* kvb  = d_in[9];
  const void* ow1  = d_in[10];
  const void* ob1  = d_in[11];
  const void* ow2  = d_in[12];
  const void* ob2  = d_in[13];
  const void* lg   = d_in[14];
  const void* lb   = d_in[15];
  const int*  srcI = (const int*)d_in[16];
  const int*  dstI = srcI + NE;

  char* ws = (char*)d_ws;
  size_t off = 0;
  auto alloc = [&](size_t bytes) -> void* {
    void* p = ws + off;
    off = (off + bytes + 255) & ~(size_t)255;
    return p;
  };
  int*    flag  = (int*)   alloc(4);
  ushort* NFc   = (ushort*)alloc((size_t)NN * 128 * 2);
  ushort* SB    = (ushort*)alloc(8 * 128 * 2);
  ushort* KVW2  = (ushort*)alloc(64 * 128 * 2);
  ushort* W1aT  = (ushort*)alloc(128 * 128 * 2);
  ushort* W1bT  = (ushort*)alloc(128 * 128 * 2);
  ushort* W1cT  = (ushort*)alloc(128 * 64 * 2);
  ushort* W2T   = (ushort*)alloc(128 * 128 * 2);
  ushort* QT    = (ushort*)alloc(128 * 128 * 2);
  ushort* KVT   = (ushort*)alloc(128 * 128 * 2);
  ushort* O1T   = (ushort*)alloc(128 * 256 * 2);
  ushort* O2T   = (ushort*)alloc(128 * 128 * 2);
  int*    last  = (int*)   alloc(NN * 4);
  int*    cnt   = (int*)   alloc(NN * 4);
  int*    fill  = (int*)   alloc(NN * 4);
  int*    pos   = (int*)   alloc((size_t)NE * 4);
  int*    sSort = (int*)   alloc((size_t)NE * 4);
  int*    dSort = (int*)   alloc((size_t)NE * 4);
  ushort* EAs   = (ushort*)alloc((size_t)NE * 64 * 2);
  float*  attn  = (float*) alloc(NN * 8 * 4);
  uint*   Menc  = (uint*)  alloc(8 * 4);
  float*  S     = (float*) alloc(8 * 4);
  ushort* PA    = (ushort*)alloc((size_t)NN * 128 * 2);
  ushort* PB    = (ushort*)alloc((size_t)NN * 128 * 2);
  ushort* Qb    = (ushort*)alloc((size_t)NN * 128 * 2);
  ushort* KV1   = (ushort*)alloc((size_t)NN * 128 * 2);
  float*  Gagg  = (float*) alloc((size_t)NN * 128 * 4);
  ushort* h_in  = (ushort*)alloc((size_t)NN * 256 * 2);
  ushort* T1    = (ushort*)alloc((size_t)NN * 128 * 2);

  k_detect<<<1, 256, 0, stream>>>((const uint*)NF0, flag);
  k_prep<<<3159, 256, 0, stream>>>(NF0, w1, w2, qw, kvw, ow1, ow2,
                                   b1, b2, qb, kvb, ob1, ob2, lg, lb,
                                   NFc, Gagg, last, cnt, Menc, S, SB, KVW2,
                                   W1aT, W1bT, W1cT, W2T, QT, KVT, O1T, O2T, flag);
  k_count<<<1250, 256, 0, stream>>>(dstI, cnt, last);
  k_scan<<<1, 1024, 0, stream>>>(cnt, fill);
  k_fill<<<1250, 256, 0, stream>>>(srcI, dstI, fill, pos, sSort, dSort);
  k_perm<<<2500, 256, 0, stream>>>((const float*)EA0, (const ushort*)EA0, pos, EAs, flag);
  k_nodepack<<<625, 256, 0, stream>>>(NFc, W1aT, W1bT, QT, KVT, SB, PA, PB, Qb, KV1);
  k_edge<<<2500, 256, 0, stream>>>(PA, PB, EAs, sSort, dSort, W1cT, Gagg);
  k_attn<<<625, 256, 0, stream>>>(Qb, KV1, (const ushort*)EA0, (const float*)EA0,
                                  KVW2, srcI, last, attn, Menc, flag);
  k_asum<<<40, 256, 0, stream>>>(attn, last, Menc, S);
  k_aggmm<<<157, 256, 0, stream>>>(Gagg, W2T, SB, cnt, last, attn, Menc, S, NFc, h_in);
  k_gemm<256, 1><<<157, 256, 0, stream>>>(h_in, O1T, SB + 512, T1, NN);
  k_out2ln<<<157, 256, 0, stream>>>(T1, O2T, SB, NFc, d_out, flag);
}